// Round 5
// baseline (138.301 us; speedup 1.0000x reference)
//
#include <hip/hip_runtime.h>
#include <hip/hip_fp16.h>
#include <cstdint>
#include <cstddef>

// z = soft_thresh(Toeplitz(v) @ x + W2 @ y, beta)  -- complex, N=1024, M=256, B=1024
// Real embedding: C[1024][2048] = A'[1024][2560] @ B'[2560][2048], where
//   A' = [W1_re | W2_re | W1_im | W2_im]
//   B' col 2n   = [x_re; y_re; -x_im; -y_im](:,n)
//   B' col 2n+1 = [x_im; y_im;  x_re;  y_re](:,n)
// => C[i][2n]=Re z[i][n], C[i][2n+1]=Im z[i][n].
// B' stored transposed (Bt[2048][2560], k-contiguous) for MFMA NT layout.
//
// R4 finding: harness output = Re(z) ONLY: [1024,1024] f32, out_size=1048576.
// (R1-R3 SIGABRTs were d_out OOB from the 8MB interleaved write; guard fixed.)
// R5 change: epilogue stores only even C'-columns at out[row*1024 + col/2].
// Im is still computed (needed for |z| in the soft-threshold).

#define K_DIM 2560
#define BETA_F 0.01f
#define EPS_F  1e-12f

typedef __attribute__((ext_vector_type(8))) _Float16 half8;
typedef __attribute__((ext_vector_type(4))) float   floatx4;

// Static device-side staging buffers (allocated at module load; graph-safe).
__device__ alignas(16) _Float16 g_Ap[1024 * K_DIM];   // 5 MB
__device__ alignas(16) _Float16 g_Bt[2048 * K_DIM];   // 10 MB

// ---------------- prep 1: build A' (Toeplitz from v + W2 copy), f32 -> f16 ----
__global__ __launch_bounds__(256) void build_A(
    const float* __restrict__ v_re, const float* __restrict__ v_im,
    const float* __restrict__ W2_re, const float* __restrict__ W2_im)
{
    int t = blockIdx.x * 256 + threadIdx.x;   // one thread per pair of elements
    int i  = t / 1280;
    int kp = (t - i * 1280) * 2;
    _Float16 h0, h1;
#pragma unroll
    for (int e = 0; e < 2; ++e) {
        int k = kp + e;
        float val;
        if (k < 1024)       val = v_re[1023 + i - k];            // W1_re[i][k]
        else if (k < 1280)  val = W2_re[i * 256 + (k - 1024)];   // W2_re[i][k']
        else if (k < 2304)  val = v_im[1023 + i - (k - 1280)];   // W1_im[i][k']
        else                val = W2_im[i * 256 + (k - 2304)];   // W2_im[i][k']
        if (e == 0) h0 = (_Float16)val; else h1 = (_Float16)val;
    }
    g_Ap[(size_t)i * K_DIM + kp]     = h0;
    g_Ap[(size_t)i * K_DIM + kp + 1] = h1;
}

// ---------------- prep 2: transposing build of Bt (f32 -> f16, 4 dests) -------
__global__ __launch_bounds__(256) void build_Bt(
    const float* __restrict__ src_re, const float* __restrict__ src_im,
    int koff)
{
    __shared__ float lre[32][33];
    __shared__ float lim[32][33];
    int tx = threadIdx.x;            // 0..31
    int ty = threadIdx.y;            // 0..7
    int k0 = blockIdx.x * 32;
    int n0 = blockIdx.y * 32;
#pragma unroll
    for (int s = 0; s < 4; ++s) {
        int kk = ty + 8 * s;
        lre[kk][tx] = src_re[(size_t)(k0 + kk) * 1024 + n0 + tx];
        lim[kk][tx] = src_im[(size_t)(k0 + kk) * 1024 + n0 + tx];
    }
    __syncthreads();
#pragma unroll
    for (int s = 0; s < 4; ++s) {
        int c = ty + 8 * s;
        int n = n0 + c;
        float re = lre[tx][c];
        float im = lim[tx][c];
        size_t k = (size_t)koff + k0 + tx;
        _Float16* r0 = g_Bt + (size_t)(2 * n)     * K_DIM;
        _Float16* r1 = g_Bt + (size_t)(2 * n + 1) * K_DIM;
        r0[k]        = (_Float16)re;        // Br block of re-col
        r0[k + 1280] = (_Float16)(-im);     // -Bi block of re-col
        r1[k]        = (_Float16)im;        // Bi block of im-col
        r1[k + 1280] = (_Float16)re;        // Br block of im-col
    }
}

// ---------------- fused GEMM + complex soft-threshold ------------------------
// 128(M) x 64(N) tile, BK=32, 256 threads = 4 waves (2x2), 16x16x32 f16 MFMA.
// Staging: per-lane half8 global load -> LDS store with XOR chunk swizzle on
// the WRITE side, so ds_read_b128 at MFMA time is 2-way (free).
__global__ __launch_bounds__(256) void gemm_fused(float* __restrict__ out,
                                                  int out_n)
{
    __shared__ __align__(16) _Float16 As[128 * 32];  // rows of 64B, chunk-swizzled
    __shared__ __align__(16) _Float16 Bs[64 * 32];

    const int tid  = threadIdx.x;
    const int lane = tid & 63;
    const int w    = tid >> 6;       // 0..3
    const int wm   = w >> 1;         // 0..1 : 64-row slab
    const int wn   = w & 1;          // 0..1 : 32-col slab

    const int bid = blockIdx.x;      // 256 blocks
    const int i0  = (bid & 7) * 128; // m-block: bid%8 -> same XCD keeps same A rows
    const int n0  = (bid >> 3) * 64; // n-block 0..31

    const _Float16* __restrict__ Ap = g_Ap;
    const _Float16* __restrict__ Bt = g_Bt;

    floatx4 acc[4][2];
#pragma unroll
    for (int a = 0; a < 4; ++a)
#pragma unroll
        for (int b = 0; b < 2; ++b) acc[a][b] = (floatx4)0.0f;

    // staging geometry: thread t handles row rS, 16B chunk jS of a tile row.
    const int rS = tid >> 2;                  // 0..63
    const int jS = tid & 3;                   // chunk in row
    // swizzle for LDS write: s = ((row mod 16)>>1)&3; LDS chunk = jS ^ s
    // ds_read geometry (must invert the same swizzle):
    const int rowA = lane & 15;
    const int q    = lane >> 4;
    const int coff = (q ^ ((rowA >> 1) & 3)) * 16;   // swizzled byte offset

    for (int kt = 0; kt < K_DIM / 32; ++kt) {
        const int k0 = kt * 32;
        // ---- stage: A 128 rows x 64B (two passes), B 64 rows x 64B ----
        half8 tA0, tA1, tB;
        tA0 = *reinterpret_cast<const half8*>(
            Ap + (size_t)(i0 + rS) * K_DIM + k0 + jS * 8);
        tA1 = *reinterpret_cast<const half8*>(
            Ap + (size_t)(i0 + rS + 64) * K_DIM + k0 + jS * 8);
        tB  = *reinterpret_cast<const half8*>(
            Bt + (size_t)(n0 + rS) * K_DIM + k0 + jS * 8);
        {
            int s0 = ((rS & 15) >> 1) & 3;
            *reinterpret_cast<half8*>((char*)As + rS * 64 + (jS ^ s0) * 16) = tA0;
            *reinterpret_cast<half8*>((char*)As + (rS + 64) * 64 + (jS ^ s0) * 16) = tA1;
            *reinterpret_cast<half8*>((char*)Bs + rS * 64 + (jS ^ s0) * 16) = tB;
        }
        __syncthreads();   // LDS tiles ready

        half8 a[4], b[2];
#pragma unroll
        for (int mi = 0; mi < 4; ++mi) {
            int r = wm * 64 + mi * 16 + rowA;
            a[mi] = *reinterpret_cast<const half8*>((const char*)As + r * 64 + coff);
        }
#pragma unroll
        for (int ni = 0; ni < 2; ++ni) {
            int r = wn * 32 + ni * 16 + rowA;
            b[ni] = *reinterpret_cast<const half8*>((const char*)Bs + r * 64 + coff);
        }
#pragma unroll
        for (int mi = 0; mi < 4; ++mi)
#pragma unroll
            for (int ni = 0; ni < 2; ++ni)
                acc[mi][ni] = __builtin_amdgcn_mfma_f32_16x16x32_f16(
                    a[mi], b[ni], acc[mi][ni], 0, 0, 0);
        __syncthreads();   // all waves done reading before next overwrite
    }

    // epilogue: C/D layout col=lane&15, row=(lane>>4)*4+reg. Adjacent lanes
    // (lane^1) hold the re/im pair of one complex z -> soft-threshold via shfl.
    // Output = Re(z) only: even C'-columns store at out[row*1024 + col/2].
    const int colL  = lane & 15;
    const int rquad = (lane >> 4) * 4;
#pragma unroll
    for (int mi = 0; mi < 4; ++mi)
#pragma unroll
        for (int ni = 0; ni < 2; ++ni)
#pragma unroll
            for (int r = 0; r < 4; ++r) {
                float c = acc[mi][ni][r];
                float p = __shfl_xor(c, 1, 64);
                float mag = sqrtf(c * c + p * p);
                float s = fmaxf(mag - BETA_F, 0.0f) / fmaxf(mag, EPS_F);
                int row = i0 + wm * 64 + mi * 16 + rquad + r;
                int col = n0 + wn * 32 + ni * 16 + colL;   // C' column (0..2047)
                if ((col & 1) == 0) {                       // even = Re lane
                    size_t idx = (size_t)row * 1024 + (col >> 1);
                    if (idx < (size_t)out_n) out[idx] = c * s;
                }
            }
}

// ---------------- launcher ---------------------------------------------------
extern "C" void kernel_launch(void* const* d_in, const int* in_sizes, int n_in,
                              void* d_out, int out_size, void* d_ws, size_t ws_size,
                              hipStream_t stream) {
    (void)d_ws; (void)ws_size; (void)in_sizes; (void)n_in;
    const float* v_re  = (const float*)d_in[0];
    const float* v_im  = (const float*)d_in[1];
    const float* W2_re = (const float*)d_in[2];
    const float* W2_im = (const float*)d_in[3];
    const float* x_re  = (const float*)d_in[4];
    const float* x_im  = (const float*)d_in[5];
    const float* y_re  = (const float*)d_in[6];
    const float* y_im  = (const float*)d_in[7];
    float* out = (float*)d_out;

    build_A<<<5120, 256, 0, stream>>>(v_re, v_im, W2_re, W2_im);
    build_Bt<<<dim3(32, 32), dim3(32, 8), 0, stream>>>(x_re, x_im, 0);
    build_Bt<<<dim3(8, 32),  dim3(32, 8), 0, stream>>>(y_re, y_im, 1024);
    gemm_fused<<<256, 256, 0, stream>>>(out, out_size);
}

// Round 6
// 117.300 us; speedup vs baseline: 1.1790x; 1.1790x over previous
//
#include <hip/hip_runtime.h>
#include <hip/hip_fp16.h>
#include <cstdint>
#include <cstddef>

// z = soft_thresh(Toeplitz(v) @ x + W2 @ y, beta) -- complex, N=1024, M=256, B=1024
// Real embedding: C[1024][2048] = A'[1024][2560] @ B'[2560][2048] (layouts in R0-R5).
// Output = Re(z) only: [1024,1024] f32 (R4 finding).
//
// R6: attack latency-bound gemm (R5: MfmaUtil 6.9%, Occ 10%, 1 block/CU):
//  - 64x64 tile, BK=64 -> 512 blocks = 2 blocks/CU, 8 waves/CU
//  - register prefetch of next K-slab between the two barriers
//  - XCD-aware super-tiling: blocks on one XCD share A and B slabs in L2
//  - prep kernels: vectorized stores (half8/half4 instead of 2-4B scalars)

#define K_DIM 2560
#define BETA_F 0.01f
#define EPS_F  1e-12f

typedef __attribute__((ext_vector_type(8))) _Float16 half8;
typedef __attribute__((ext_vector_type(4))) _Float16 half4;
typedef __attribute__((ext_vector_type(4))) float   floatx4;

__device__ alignas(16) _Float16 g_Ap[1024 * K_DIM];   // 5 MB
__device__ alignas(16) _Float16 g_Bt[2048 * K_DIM];   // 10 MB

// ---------------- prep 1: build A' (Toeplitz + W2), 16B stores ---------------
__global__ __launch_bounds__(256) void build_A(
    const float* __restrict__ v_re, const float* __restrict__ v_im,
    const float* __restrict__ W2_re, const float* __restrict__ W2_im)
{
    int t = blockIdx.x * 256 + threadIdx.x;   // 327680 threads, 8 halves each
    int i  = t / 320;
    int c  = t - i * 320;
    int kp = c * 8;                            // segment-aligned (all bounds %8==0)
    half8 h;
    if (kp < 1024) {
#pragma unroll
        for (int j = 0; j < 8; ++j) h[j] = (_Float16)v_re[1023 + i - kp - j];
    } else if (kp < 1280) {
        const float* s = W2_re + i * 256 + (kp - 1024);
#pragma unroll
        for (int j = 0; j < 8; ++j) h[j] = (_Float16)s[j];
    } else if (kp < 2304) {
        int k2 = kp - 1280;
#pragma unroll
        for (int j = 0; j < 8; ++j) h[j] = (_Float16)v_im[1023 + i - k2 - j];
    } else {
        const float* s = W2_im + i * 256 + (kp - 2304);
#pragma unroll
        for (int j = 0; j < 8; ++j) h[j] = (_Float16)s[j];
    }
    *reinterpret_cast<half8*>(g_Ap + (size_t)i * K_DIM + kp) = h;
}

// ---------------- prep 2: transposing build of Bt, half4 (8B) stores ---------
__global__ __launch_bounds__(256) void build_Bt(
    const float* __restrict__ src_re, const float* __restrict__ src_im,
    int koff)
{
    __shared__ float lre[32][33];
    __shared__ float lim[32][33];
    int tid = threadIdx.x;
    int tx = tid & 31, ty = tid >> 5;          // ty 0..7
    int k0 = blockIdx.x * 32;
    int n0 = blockIdx.y * 32;
#pragma unroll
    for (int s = 0; s < 4; ++s) {
        int kk = ty + 8 * s;
        lre[kk][tx] = src_re[(size_t)(k0 + kk) * 1024 + n0 + tx];
        lim[kk][tx] = src_im[(size_t)(k0 + kk) * 1024 + n0 + tx];
    }
    __syncthreads();
    int lane_n = tid >> 3;                     // 0..31
    int kq     = (tid & 7) * 4;                // 0,4,...,28
    half4 hre, him, hmim;
#pragma unroll
    for (int j = 0; j < 4; ++j) {
        float re = lre[kq + j][lane_n];
        float im = lim[kq + j][lane_n];
        hre[j]  = (_Float16)re;
        him[j]  = (_Float16)im;
        hmim[j] = (_Float16)(-im);
    }
    int n = n0 + lane_n;
    size_t kk2 = (size_t)koff + k0 + kq;
    _Float16* r0 = g_Bt + (size_t)(2 * n)     * K_DIM;
    _Float16* r1 = g_Bt + (size_t)(2 * n + 1) * K_DIM;
    *reinterpret_cast<half4*>(r0 + kk2)        = hre;   // Br block of re-col
    *reinterpret_cast<half4*>(r0 + kk2 + 1280) = hmim;  // -Bi block of re-col
    *reinterpret_cast<half4*>(r1 + kk2)        = him;   // Bi block of im-col
    *reinterpret_cast<half4*>(r1 + kk2 + 1280) = hre;   // Br block of im-col
}

// ---------------- fused GEMM + complex soft-threshold ------------------------
// 64x64 tile, BK=64 (two 32-k sub-tiles), 512 blocks, 256 thr = 4 waves (2x2),
// each wave 32x32 (2x2 acc). Register prefetch of next slab between barriers.
// LDS layout per sub-tile: 64 rows x 64B, XOR chunk swizzle (R5: 0 conflicts).
__global__ __launch_bounds__(256) void gemm_fused(float* __restrict__ out,
                                                  int out_n)
{
    __shared__ __align__(16) _Float16 As[2 * 64 * 32];  // [sub][row][32h]
    __shared__ __align__(16) _Float16 Bs[2 * 64 * 32];

    const int tid  = threadIdx.x;
    const int lane = tid & 63;
    const int w    = tid >> 6;
    const int wm   = w >> 1;         // m-half (32 rows)
    const int wn   = w & 1;          // n-half (32 cols)

    // XCD-aware mapping: xcd=bid&7 (round-robin dispatch); each XCD owns an
    // 8m x 8n super-tile so its 64 blocks share A/B slabs in the XCD's L2.
    const int bid = blockIdx.x;      // 0..511
    const int xcd = bid & 7;
    const int t   = bid >> 3;        // 0..63
    const int mi0 = ((xcd & 1) * 8 + (t & 7)) * 64;   // 0..960
    const int ni0 = ((xcd >> 1) * 8 + (t >> 3)) * 64; // 0..1984

    floatx4 acc[2][2];
#pragma unroll
    for (int a = 0; a < 2; ++a)
#pragma unroll
        for (int b = 0; b < 2; ++b) acc[a][b] = (floatx4)0.0f;

    // staging: thread -> row rS (0..63), 16B chunk jS of each 64B sub-row
    const int rS = tid >> 2;
    const int jS = tid & 3;
    const int s0 = ((rS & 15) >> 1) & 3;
    char* asW = (char*)As + rS * 64 + ((jS ^ s0) * 16);
    char* bsW = (char*)Bs + rS * 64 + ((jS ^ s0) * 16);
    const _Float16* gA = g_Ap + (size_t)(mi0 + rS) * K_DIM + jS * 8;
    const _Float16* gB = g_Bt + (size_t)(ni0 + rS) * K_DIM + jS * 8;

    // ds_read geometry (inverts the same swizzle; R5-proven, 0 conflicts)
    const int rowA = lane & 15;
    const int q    = lane >> 4;
    const int coff = (q ^ ((rowA >> 1) & 3)) * 16;

    // preload iter 0
    half8 pA0 = *reinterpret_cast<const half8*>(gA);
    half8 pA1 = *reinterpret_cast<const half8*>(gA + 32);
    half8 pB0 = *reinterpret_cast<const half8*>(gB);
    half8 pB1 = *reinterpret_cast<const half8*>(gB + 32);

    for (int kt = 0; kt < K_DIM / 64; ++kt) {
        *reinterpret_cast<half8*>(asW)        = pA0;   // k 0..31  sub-tile
        *reinterpret_cast<half8*>(asW + 4096) = pA1;   // k 32..63 sub-tile
        *reinterpret_cast<half8*>(bsW)        = pB0;
        *reinterpret_cast<half8*>(bsW + 4096) = pB1;
        __syncthreads();
        if (kt < K_DIM / 64 - 1) {             // prefetch next slab (vmcnt wait
            const _Float16* ga = gA + (kt + 1) * 64;   //  lands at next store,
            const _Float16* gb = gB + (kt + 1) * 64;   //  covered by mfma+barrier)
            pA0 = *reinterpret_cast<const half8*>(ga);
            pA1 = *reinterpret_cast<const half8*>(ga + 32);
            pB0 = *reinterpret_cast<const half8*>(gb);
            pB1 = *reinterpret_cast<const half8*>(gb + 32);
        }
        half8 af[2][2], bf[2][2];
#pragma unroll
        for (int mi = 0; mi < 2; ++mi) {
            int r = wm * 32 + mi * 16 + rowA;
            af[mi][0] = *reinterpret_cast<const half8*>((char*)As + r * 64 + coff);
            af[mi][1] = *reinterpret_cast<const half8*>((char*)As + 4096 + r * 64 + coff);
        }
#pragma unroll
        for (int ni = 0; ni < 2; ++ni) {
            int r = wn * 32 + ni * 16 + rowA;
            bf[ni][0] = *reinterpret_cast<const half8*>((char*)Bs + r * 64 + coff);
            bf[ni][1] = *reinterpret_cast<const half8*>((char*)Bs + 4096 + r * 64 + coff);
        }
#pragma unroll
        for (int mi = 0; mi < 2; ++mi)
#pragma unroll
            for (int ni = 0; ni < 2; ++ni) {
                acc[mi][ni] = __builtin_amdgcn_mfma_f32_16x16x32_f16(
                    af[mi][0], bf[ni][0], acc[mi][ni], 0, 0, 0);
                acc[mi][ni] = __builtin_amdgcn_mfma_f32_16x16x32_f16(
                    af[mi][1], bf[ni][1], acc[mi][ni], 0, 0, 0);
            }
        __syncthreads();
    }

    // epilogue: C/D col=lane&15, row=(lane>>4)*4+reg; lane^1 = re/im partner.
    const int colL  = lane & 15;
    const int rquad = (lane >> 4) * 4;
#pragma unroll
    for (int mi = 0; mi < 2; ++mi)
#pragma unroll
        for (int ni = 0; ni < 2; ++ni)
#pragma unroll
            for (int r = 0; r < 4; ++r) {
                float c = acc[mi][ni][r];
                float p = __shfl_xor(c, 1, 64);
                float mag = sqrtf(c * c + p * p);
                float s = fmaxf(mag - BETA_F, 0.0f) / fmaxf(mag, EPS_F);
                int row = mi0 + wm * 32 + mi * 16 + rquad + r;
                int col = ni0 + wn * 32 + ni * 16 + colL;   // C' col (0..2047)
                if ((col & 1) == 0) {                        // even = Re lane
                    size_t idx = (size_t)row * 1024 + (col >> 1);
                    if (idx < (size_t)out_n) out[idx] = c * s;
                }
            }
}

// ---------------- launcher ---------------------------------------------------
extern "C" void kernel_launch(void* const* d_in, const int* in_sizes, int n_in,
                              void* d_out, int out_size, void* d_ws, size_t ws_size,
                              hipStream_t stream) {
    (void)d_ws; (void)ws_size; (void)in_sizes; (void)n_in;
    const float* v_re  = (const float*)d_in[0];
    const float* v_im  = (const float*)d_in[1];
    const float* W2_re = (const float*)d_in[2];
    const float* W2_im = (const float*)d_in[3];
    const float* x_re  = (const float*)d_in[4];
    const float* x_im  = (const float*)d_in[5];
    const float* y_re  = (const float*)d_in[6];
    const float* y_im  = (const float*)d_in[7];
    float* out = (float*)d_out;

    build_A<<<1280, 256, 0, stream>>>(v_re, v_im, W2_re, W2_im);
    build_Bt<<<dim3(32, 32), 256, 0, stream>>>(x_re, x_im, 0);
    build_Bt<<<dim3(8, 32),  256, 0, stream>>>(y_re, y_im, 1024);
    gemm_fused<<<512, 256, 0, stream>>>(out, out_size);
}

// Round 7
// 116.907 us; speedup vs baseline: 1.1830x; 1.0034x over previous
//
#include <hip/hip_runtime.h>
#include <hip/hip_fp16.h>
#include <cstdint>
#include <cstddef>

// z = soft_thresh(Toeplitz(v) @ x + W2 @ y, beta) -- complex, N=1024, M=256, B=1024
// Real embedding: C[1024][2048] = A'[1024][2560] @ B'[2560][2048] (layouts R0-R5).
// Output = Re(z) only: [1024,1024] f32 (R4 finding).
//
// R7 (R6 was grid-capped at 20% occupancy, MfmaUtil 9% -> latency-bound):
//  - split-K=2 at k=1280: 1024 blocks (4/CU, 16 waves/CU), 20 iters each
//  - double-buffered LDS, ONE barrier per K-iter
//  - partials in static f32 buffers (store-only, no atomics)
//  - new fused reduce + soft-threshold epilogue (float4, 16MB->4MB)
//  - build_Bt x/y merged into one dispatch

#define K_DIM 2560
#define BETA_F 0.01f
#define EPS_F  1e-12f

typedef __attribute__((ext_vector_type(8))) _Float16 half8;
typedef __attribute__((ext_vector_type(4))) _Float16 half4;
typedef __attribute__((ext_vector_type(4))) float   floatx4;

__device__ alignas(16) _Float16 g_Ap[1024 * K_DIM];     // 5 MB
__device__ alignas(16) _Float16 g_Bt[2048 * K_DIM];     // 10 MB
__device__ alignas(16) float    g_P0[1024 * 2048];      // 8 MB split-0 partial
__device__ alignas(16) float    g_P1[1024 * 2048];      // 8 MB split-1 partial

// ---------------- prep 1: build A' (Toeplitz + W2), 16B stores ---------------
__global__ __launch_bounds__(256) void build_A(
    const float* __restrict__ v_re, const float* __restrict__ v_im,
    const float* __restrict__ W2_re, const float* __restrict__ W2_im)
{
    int t = blockIdx.x * 256 + threadIdx.x;   // 327680 threads, 8 halves each
    int i  = t / 320;
    int c  = t - i * 320;
    int kp = c * 8;                            // segment-aligned
    half8 h;
    if (kp < 1024) {
#pragma unroll
        for (int j = 0; j < 8; ++j) h[j] = (_Float16)v_re[1023 + i - kp - j];
    } else if (kp < 1280) {
        const float* s = W2_re + i * 256 + (kp - 1024);
#pragma unroll
        for (int j = 0; j < 8; ++j) h[j] = (_Float16)s[j];
    } else if (kp < 2304) {
        int k2 = kp - 1280;
#pragma unroll
        for (int j = 0; j < 8; ++j) h[j] = (_Float16)v_im[1023 + i - k2 - j];
    } else {
        const float* s = W2_im + i * 256 + (kp - 2304);
#pragma unroll
        for (int j = 0; j < 8; ++j) h[j] = (_Float16)s[j];
    }
    *reinterpret_cast<half8*>(g_Ap + (size_t)i * K_DIM + kp) = h;
}

// ---------------- prep 2: transposing build of Bt (x and y in one launch) ----
__global__ __launch_bounds__(256) void build_Bt(
    const float* __restrict__ x_re, const float* __restrict__ x_im,
    const float* __restrict__ y_re, const float* __restrict__ y_im)
{
    __shared__ float lre[32][33];
    __shared__ float lim[32][33];
    int tid = threadIdx.x;
    int tx = tid & 31, ty = tid >> 5;          // ty 0..7
    int bx = blockIdx.x;                        // 0..39: 0..31 -> x, 32..39 -> y
    const float* sre = (bx < 32) ? x_re : y_re;
    const float* sim = (bx < 32) ? x_im : y_im;
    int kb   = (bx < 32) ? bx : (bx - 32);
    int koff = (bx < 32) ? 0 : 1024;
    int k0 = kb * 32;
    int n0 = blockIdx.y * 32;
#pragma unroll
    for (int s = 0; s < 4; ++s) {
        int kk = ty + 8 * s;
        lre[kk][tx] = sre[(size_t)(k0 + kk) * 1024 + n0 + tx];
        lim[kk][tx] = sim[(size_t)(k0 + kk) * 1024 + n0 + tx];
    }
    __syncthreads();
    int lane_n = tid >> 3;                     // 0..31
    int kq     = (tid & 7) * 4;                // 0,4,...,28
    half4 hre, him, hmim;
#pragma unroll
    for (int j = 0; j < 4; ++j) {
        float re = lre[kq + j][lane_n];
        float im = lim[kq + j][lane_n];
        hre[j]  = (_Float16)re;
        him[j]  = (_Float16)im;
        hmim[j] = (_Float16)(-im);
    }
    int n = n0 + lane_n;
    size_t kk2 = (size_t)koff + k0 + kq;
    _Float16* r0 = g_Bt + (size_t)(2 * n)     * K_DIM;
    _Float16* r1 = g_Bt + (size_t)(2 * n + 1) * K_DIM;
    *reinterpret_cast<half4*>(r0 + kk2)        = hre;   // Br block of re-col
    *reinterpret_cast<half4*>(r0 + kk2 + 1280) = hmim;  // -Bi block of re-col
    *reinterpret_cast<half4*>(r1 + kk2)        = him;   // Bi block of im-col
    *reinterpret_cast<half4*>(r1 + kk2 + 1280) = hre;   // Br block of im-col
}

// ---------------- split-K GEMM (partials only) -------------------------------
// 64x64 tile, BK=64, split-K=2 (k offset 0 / 1280), 1024 blocks, 4 waves (2x2
// of 32x32). Double-buffered LDS, one barrier per iter. XOR swizzle (0-confl).
__global__ __launch_bounds__(256) void gemm_split(void)
{
    __shared__ __align__(16) _Float16 As[2 * 2 * 64 * 32];  // [buf][ksub][row][32h]
    __shared__ __align__(16) _Float16 Bs[2 * 2 * 64 * 32];

    const int tid  = threadIdx.x;
    const int lane = tid & 63;
    const int w    = tid >> 6;
    const int wm   = w >> 1;
    const int wn   = w & 1;

    const int bid   = blockIdx.x;        // 0..1023
    const int split = bid >> 9;          // 0/1 -> k-offset 0 / 1280
    const int sb    = bid & 511;
    const int xcd   = sb & 7;            // XCD round-robin; 8m x 8n super-tile
    const int t     = sb >> 3;           // 0..63
    const int mi0 = ((xcd & 1) * 8 + (t & 7)) * 64;    // 0..960
    const int ni0 = ((xcd >> 1) * 8 + (t >> 3)) * 64;  // 0..1984
    const int ks  = split * 1280;
    float* __restrict__ P = split ? g_P1 : g_P0;

    floatx4 acc[2][2];
#pragma unroll
    for (int a = 0; a < 2; ++a)
#pragma unroll
        for (int b = 0; b < 2; ++b) acc[a][b] = (floatx4)0.0f;

    // staging: thread -> row rS (0..63), 16B chunk jS of each 64B sub-row
    const int rS = tid >> 2;
    const int jS = tid & 3;
    const int s0 = ((rS & 15) >> 1) & 3;
    char* asW = (char*)As + rS * 64 + ((jS ^ s0) * 16);
    char* bsW = (char*)Bs + rS * 64 + ((jS ^ s0) * 16);
    const _Float16* gA = g_Ap + (size_t)(mi0 + rS) * K_DIM + ks + jS * 8;
    const _Float16* gB = g_Bt + (size_t)(ni0 + rS) * K_DIM + ks + jS * 8;

    // ds_read geometry (inverts the swizzle; verified 0 conflicts R5/R6)
    const int rowA = lane & 15;
    const int q    = lane >> 4;
    const int coff = (q ^ ((rowA >> 1) & 3)) * 16;

    // preload iter 0 -> buf 0
    {
        half8 pA0 = *reinterpret_cast<const half8*>(gA);
        half8 pA1 = *reinterpret_cast<const half8*>(gA + 32);
        half8 pB0 = *reinterpret_cast<const half8*>(gB);
        half8 pB1 = *reinterpret_cast<const half8*>(gB + 32);
        *reinterpret_cast<half8*>(asW)        = pA0;
        *reinterpret_cast<half8*>(asW + 4096) = pA1;
        *reinterpret_cast<half8*>(bsW)        = pB0;
        *reinterpret_cast<half8*>(bsW + 4096) = pB1;
    }
    __syncthreads();

    const int NIT = 1280 / 64;           // 20
    for (int kt = 0; kt < NIT; ++kt) {
        const int cur = kt & 1;
        half8 pA0, pA1, pB0, pB1;
        if (kt < NIT - 1) {              // issue next slab's global loads now
            const _Float16* ga = gA + (kt + 1) * 64;
            const _Float16* gb = gB + (kt + 1) * 64;
            pA0 = *reinterpret_cast<const half8*>(ga);
            pA1 = *reinterpret_cast<const half8*>(ga + 32);
            pB0 = *reinterpret_cast<const half8*>(gb);
            pB1 = *reinterpret_cast<const half8*>(gb + 32);
        }
        const char* Ab = (const char*)As + cur * 8192;
        const char* Bb = (const char*)Bs + cur * 8192;
        half8 af[2][2], bf[2][2];
#pragma unroll
        for (int mi = 0; mi < 2; ++mi) {
            int r = wm * 32 + mi * 16 + rowA;
            af[mi][0] = *reinterpret_cast<const half8*>(Ab + r * 64 + coff);
            af[mi][1] = *reinterpret_cast<const half8*>(Ab + 4096 + r * 64 + coff);
        }
#pragma unroll
        for (int ni = 0; ni < 2; ++ni) {
            int r = wn * 32 + ni * 16 + rowA;
            bf[ni][0] = *reinterpret_cast<const half8*>(Bb + r * 64 + coff);
            bf[ni][1] = *reinterpret_cast<const half8*>(Bb + 4096 + r * 64 + coff);
        }
#pragma unroll
        for (int mi = 0; mi < 2; ++mi)
#pragma unroll
            for (int ni = 0; ni < 2; ++ni) {
                acc[mi][ni] = __builtin_amdgcn_mfma_f32_16x16x32_f16(
                    af[mi][0], bf[ni][0], acc[mi][ni], 0, 0, 0);
                acc[mi][ni] = __builtin_amdgcn_mfma_f32_16x16x32_f16(
                    af[mi][1], bf[ni][1], acc[mi][ni], 0, 0, 0);
            }
        if (kt < NIT - 1) {              // store prefetch into the other buffer
            char* aw = asW + (cur ^ 1) * 8192;
            char* bw = bsW + (cur ^ 1) * 8192;
            *reinterpret_cast<half8*>(aw)        = pA0;
            *reinterpret_cast<half8*>(aw + 4096) = pA1;
            *reinterpret_cast<half8*>(bw)        = pB0;
            *reinterpret_cast<half8*>(bw + 4096) = pB1;
        }
        __syncthreads();                 // single barrier per iter
    }

    // store f32 partial tile (C/D layout: col=lane&15, row=(lane>>4)*4+reg)
    const int colL  = lane & 15;
    const int rquad = (lane >> 4) * 4;
#pragma unroll
    for (int mi = 0; mi < 2; ++mi)
#pragma unroll
        for (int ni = 0; ni < 2; ++ni)
#pragma unroll
            for (int r = 0; r < 4; ++r) {
                int row = mi0 + wm * 32 + mi * 16 + rquad + r;
                int col = ni0 + wn * 32 + ni * 16 + colL;
                P[(size_t)row * 2048 + col] = acc[mi][ni][r];
            }
}

// ---------------- epilogue: reduce splits + complex soft-threshold ----------
// C'[i][2n]=Re z, C'[i][2n+1]=Im z. Each thread: one float4 = 2 complex.
__global__ __launch_bounds__(256) void reduce_soft(float* __restrict__ out,
                                                   int out_n)
{
    int t = blockIdx.x * 256 + threadIdx.x;          // 0..524287
    floatx4 v0 = reinterpret_cast<const floatx4*>(g_P0)[t];
    floatx4 v1 = reinterpret_cast<const floatx4*>(g_P1)[t];
    float re0 = v0[0] + v1[0], im0 = v0[1] + v1[1];
    float re1 = v0[2] + v1[2], im1 = v0[3] + v1[3];
    float m0 = sqrtf(re0 * re0 + im0 * im0);
    float m1 = sqrtf(re1 * re1 + im1 * im1);
    float s0 = fmaxf(m0 - BETA_F, 0.0f) / fmaxf(m0, EPS_F);
    float s1 = fmaxf(m1 - BETA_F, 0.0f) / fmaxf(m1, EPS_F);
    float2 r = make_float2(re0 * s0, re1 * s1);
    int idx = t * 2;                                  // flat Re-output index
    if (idx + 1 < out_n)
        *reinterpret_cast<float2*>(out + idx) = r;
}

// ---------------- launcher ---------------------------------------------------
extern "C" void kernel_launch(void* const* d_in, const int* in_sizes, int n_in,
                              void* d_out, int out_size, void* d_ws, size_t ws_size,
                              hipStream_t stream) {
    (void)d_ws; (void)ws_size; (void)in_sizes; (void)n_in;
    const float* v_re  = (const float*)d_in[0];
    const float* v_im  = (const float*)d_in[1];
    const float* W2_re = (const float*)d_in[2];
    const float* W2_im = (const float*)d_in[3];
    const float* x_re  = (const float*)d_in[4];
    const float* x_im  = (const float*)d_in[5];
    const float* y_re  = (const float*)d_in[6];
    const float* y_im  = (const float*)d_in[7];
    float* out = (float*)d_out;

    build_A<<<1280, 256, 0, stream>>>(v_re, v_im, W2_re, W2_im);
    build_Bt<<<dim3(40, 32), 256, 0, stream>>>(x_re, x_im, y_re, y_im);
    gemm_split<<<1024, 256, 0, stream>>>();
    reduce_soft<<<2048, 256, 0, stream>>>(out, out_size);
}